// Round 2
// baseline (20232.979 us; speedup 1.0000x reference)
//
#include <hip/hip_runtime.h>
#include <cmath>

#define B 8
#define T 64
#define IN_DIM 128
#define OUT_DIM 256
#define N_IN 32
#define N_DYN 32
#define N_STAT 160
#define NN 192
#define H 256
#define KQ 256
#define SS 256
#define IDX0 128

__device__ __forceinline__ float sigmoidf_(float x) { return 1.0f / (1.0f + expf(-x)); }

// K1: q_dyn / k_dyn = h[:,160+n,:] @ W[n] + b[n]
__global__ void k_qkdyn(const float* __restrict__ h,
                        const float* __restrict__ wq, const float* __restrict__ bq,
                        const float* __restrict__ wk, const float* __restrict__ bk,
                        float* __restrict__ qd, float* __restrict__ kd)
{
    int n = blockIdx.y, which = blockIdx.x, tid = threadIdx.x;
    const float* W    = which ? wk : wq;
    const float* bias = which ? bk : bq;
    float* out        = which ? kd : qd;
    __shared__ float hs[B][H];
    for (int idx = tid; idx < B * H; idx += 256) {
        int b = idx >> 8, col = idx & 255;
        hs[b][col] = h[((size_t)b * NN + N_STAT + n) * H + col];
    }
    __syncthreads();
    float acc[B] = {};
    const float* Wp = W + (size_t)n * H * KQ + tid;
    for (int k = 0; k < H; ++k) {
        float w = Wp[(size_t)k * KQ];
#pragma unroll
        for (int b = 0; b < B; ++b) acc[b] += hs[b][k] * w;
    }
    float bv = bias[n * KQ + tid];
    for (int b = 0; b < B; ++b)
        out[((size_t)b * N_DYN + n) * KQ + tid] = acc[b] + bv;
}

// K2: one block per (b, q-row in [32,192)); scores -> softmax -> ctx row
__global__ void k_attn_ctx(const float* __restrict__ q_static, const float* __restrict__ k_static,
                           const float* __restrict__ qd, const float* __restrict__ kd,
                           const float* __restrict__ prev, float* __restrict__ ctx)
{
    int qo = blockIdx.x;   // 0..159 -> q = 32+qo
    int b  = blockIdx.y;
    int tid = threadIdx.x;
    int q = N_IN + qo;
    __shared__ float qrow[KQ];
    __shared__ float attn_s[NN];
    __shared__ float red[256];
    for (int i = tid; i < KQ; i += 256)
        qrow[i] = (q < N_STAT) ? q_static[(size_t)q * KQ + i]
                               : qd[((size_t)b * N_DYN + (q - N_STAT)) * KQ + i];
    __syncthreads();
    float sc = -1e30f;
    if (tid < NN) {
        const float* krow = (tid < N_STAT) ? (k_static + (size_t)tid * KQ)
                                           : (kd + ((size_t)b * N_DYN + tid - N_STAT) * KQ);
        float d = 0.f;
        for (int i = 0; i < KQ; ++i) d += qrow[i] * krow[i];
        sc = d * 0.0625f;   // 1/sqrt(256)
    }
    red[tid] = sc; __syncthreads();
    for (int s = 128; s > 0; s >>= 1) { if (tid < s) red[tid] = fmaxf(red[tid], red[tid + s]); __syncthreads(); }
    float m = red[0]; __syncthreads();
    float e = (tid < NN) ? expf(sc - m) : 0.f;
    red[tid] = e; __syncthreads();
    for (int s = 128; s > 0; s >>= 1) { if (tid < s) red[tid] += red[tid + s]; __syncthreads(); }
    float inv = 1.0f / red[0];
    if (tid < NN) attn_s[tid] = e * inv;
    __syncthreads();
    float a = 0.f;
    for (int n = 0; n < NN; ++n) a += attn_s[n] * prev[((size_t)b * NN + n) * SS + tid];
    ctx[((size_t)b * 160 + qo) * SS + tid] = a;
}

// K3: lstm_in = relu(rec_in | rec_oth)
__global__ void k_rec(const float* __restrict__ x, int t,
                      const float* __restrict__ wri, const float* __restrict__ bri,
                      const float* __restrict__ wro, const float* __restrict__ bro,
                      const float* __restrict__ ctx, float* __restrict__ lin)
{
    int n = blockIdx.x, half = blockIdx.y, tid = threadIdx.x;
    int col = half * 128 + tid;
    __shared__ float ins[B][SS];
    int K; const float* W; const float* bias;
    if (n < N_IN) { K = IN_DIM; W = wri + (size_t)n * IN_DIM * H; bias = bri + (size_t)n * H; }
    else { int m = n - N_IN; K = SS; W = wro + (size_t)m * SS * H; bias = bro + (size_t)m * H; }
    for (int idx = tid; idx < B * K; idx += 128) {
        int b = idx / K, kk = idx % K;
        ins[b][kk] = (n < N_IN) ? x[((size_t)b * T + t) * IN_DIM + kk]
                                : ctx[((size_t)b * 160 + (n - N_IN)) * SS + kk];
    }
    __syncthreads();
    float acc[B] = {};
    const float* Wp = W + col;
    for (int kk = 0; kk < K; ++kk) {
        float w = Wp[(size_t)kk * H];
#pragma unroll
        for (int b = 0; b < B; ++b) acc[b] += ins[b][kk] * w;
    }
    float bv = bias[col];
    for (int b = 0; b < B; ++b)
        lin[((size_t)b * NN + n) * H + col] = fmaxf(acc[b] + bv, 0.f);
}

// K4a: gate pre-activations. Block = (n, half); 256 threads, each owns 2
// consecutive gate columns (float2 weight loads), all 8 batches.
// Writes raw (no-bias) pre-activations to gbuf[(b*NN+n)*1024 + col].
__global__ void k_gates_mm(const float* __restrict__ lin, const float* __restrict__ hcur,
                           const float* __restrict__ wih, const float* __restrict__ whh,
                           float* __restrict__ gbuf)
{
    int n = blockIdx.x, half = blockIdx.y, tid = threadIdx.x;
    int c0 = half * 512 + tid * 2;           // gate column pair
    __shared__ float in_s[B][H];
    __shared__ float h_s[B][H];
    for (int idx = tid; idx < B * H; idx += 256) {
        int b = idx >> 8, k = idx & 255;
        size_t o = ((size_t)b * NN + n) * H + k;
        in_s[b][k] = lin[o];
        h_s[b][k]  = hcur[o];
    }
    __syncthreads();
    const float* Wi = wih + (size_t)n * H * 1024 + c0;
    const float* Wh = whh + (size_t)n * H * 1024 + c0;
    float accx[B] = {}, accy[B] = {};
    for (int k = 0; k < H; ++k) {
        float2 wi = *(const float2*)(Wi + (size_t)k * 1024);
        float2 wh = *(const float2*)(Wh + (size_t)k * 1024);
#pragma unroll
        for (int b = 0; b < B; ++b) {
            float xv = in_s[b][k], hv = h_s[b][k];
            accx[b] += xv * wi.x + hv * wh.x;
            accy[b] += xv * wi.y + hv * wh.y;
        }
    }
#pragma unroll
    for (int b = 0; b < B; ++b) {
        float2 v = make_float2(accx[b], accy[b]);
        *(float2*)(gbuf + ((size_t)b * NN + n) * 1024 + c0) = v;
    }
}

// K4b: LSTM cell update from pre-activations + biases
__global__ void k_cell(const float* __restrict__ gbuf,
                       const float* __restrict__ bih, const float* __restrict__ bhh,
                       const float* __restrict__ ccur,
                       float* __restrict__ hnxt, float* __restrict__ cnxt)
{
    int n = blockIdx.x, b = blockIdx.y, c = threadIdx.x;
    const float* g = gbuf + ((size_t)b * NN + n) * 1024;
    const float* bi = bih + (size_t)n * 1024;
    const float* bh = bhh + (size_t)n * 1024;
    float gi = g[c]       + bi[c]       + bh[c];
    float gf = g[256 + c] + bi[256 + c] + bh[256 + c];
    float gg = g[512 + c] + bi[512 + c] + bh[512 + c];
    float go = g[768 + c] + bi[768 + c] + bh[768 + c];
    size_t o = ((size_t)b * NN + n) * H + c;
    float iv = sigmoidf_(gi);
    float fv = sigmoidf_(gf);
    float gv = tanhf(gg);
    float ov = sigmoidf_(go);
    float cn = fv * ccur[o] + iv * gv;
    float hn = ov * tanhf(cn);
    cnxt[o] = cn;
    hnxt[o] = hn;
}

// K5: prev_new = h_new @ w_sender + b_sender
__global__ void k_sender(const float* __restrict__ hn, const float* __restrict__ wse,
                         const float* __restrict__ bse, float* __restrict__ pn)
{
    int n = blockIdx.x, half = blockIdx.y, tid = threadIdx.x;
    int col = half * 128 + tid;
    __shared__ float hs[B][H];
    for (int idx = tid; idx < B * H; idx += 128) {
        int b = idx >> 8, k = idx & 255;
        hs[b][k] = hn[((size_t)b * NN + n) * H + k];
    }
    __syncthreads();
    float acc[B] = {};
    const float* Wp = wse + (size_t)n * H * SS + col;
    for (int k = 0; k < H; ++k) {
        float w = Wp[(size_t)k * SS];
#pragma unroll
        for (int b = 0; b < B; ++b) acc[b] += hs[b][k] * w;
    }
    float bv = bse[(size_t)n * SS + col];
    for (int b = 0; b < B; ++b)
        pn[((size_t)b * NN + n) * SS + col] = acc[b] + bv;
}

// K6: out[b,t,:] = prev_new[b,128:160,:].flat @ w_proj + b_proj  (K=8192, 4-way K-split)
__global__ void k_proj(const float* __restrict__ pn, const float* __restrict__ wp,
                       const float* __restrict__ bp, float* __restrict__ out, int t)
{
    int ot = blockIdx.x, b = blockIdx.y, tid = threadIdx.x;
    int oc = tid & 63, kq = tid >> 6;
    int o = ot * 64 + oc;
    const float* base = pn + ((size_t)b * NN + IDX0) * SS;  // 8192 contiguous acts
    float a = 0.f;
    for (int kk = kq * 2048; kk < kq * 2048 + 2048; ++kk)
        a += base[kk] * wp[(size_t)kk * OUT_DIM + o];
    __shared__ float red[4][64];
    red[kq][oc] = a;
    __syncthreads();
    if (kq == 0) {
        float s = red[0][oc] + red[1][oc] + red[2][oc] + red[3][oc] + bp[o];
        out[((size_t)b * T + t) * OUT_DIM + o] = s;
    }
}

extern "C" void kernel_launch(void* const* d_in, const int* in_sizes, int n_in,
                              void* d_out, int out_size, void* d_ws, size_t ws_size,
                              hipStream_t stream)
{
    const float* x   = (const float*)d_in[0];
    const float* wri = (const float*)d_in[1];
    const float* bri = (const float*)d_in[2];
    const float* wro = (const float*)d_in[3];
    const float* bro = (const float*)d_in[4];
    const float* wih = (const float*)d_in[5];
    const float* bih = (const float*)d_in[6];
    const float* whh = (const float*)d_in[7];
    const float* bhh = (const float*)d_in[8];
    const float* qs  = (const float*)d_in[9];
    const float* ks  = (const float*)d_in[10];
    const float* wqd = (const float*)d_in[11];
    const float* bqd = (const float*)d_in[12];
    const float* wkd = (const float*)d_in[13];
    const float* bkd = (const float*)d_in[14];
    const float* wse = (const float*)d_in[15];
    const float* bse = (const float*)d_in[16];
    const float* wp  = (const float*)d_in[17];
    const float* bp  = (const float*)d_in[18];
    float* out = (float*)d_out;

    const size_t BNH  = (size_t)B * NN * H;      // 393216
    const size_t BQK  = (size_t)B * N_DYN * KQ;  // 65536
    const size_t BCTX = (size_t)B * 160 * SS;    // 327680
    const size_t BG   = (size_t)B * NN * 1024;   // 1572864
    float* ws  = (float*)d_ws;
    float* h0  = ws;         float* c0 = h0 + BNH;  float* p0 = c0 + BNH;
    float* h1  = p0 + BNH;   float* c1 = h1 + BNH;  float* p1 = c1 + BNH;
    float* qd  = p1 + BNH;   float* kd = qd + BQK;
    float* ctx = kd + BQK;   float* lin = ctx + BCTX;
    float* gbuf = lin + BNH;
    (void)gbuf; (void)ws_size;
    // zero the recurrent state (h0,c0,p0 and ping-pong partners)
    hipMemsetAsync(d_ws, 0, 6 * BNH * sizeof(float), stream);

    for (int t = 0; t < T; ++t) {
        float* hc = (t & 1) ? h1 : h0;  float* hn = (t & 1) ? h0 : h1;
        float* cc = (t & 1) ? c1 : c0;  float* cn = (t & 1) ? c0 : c1;
        float* pc = (t & 1) ? p1 : p0;  float* px = (t & 1) ? p0 : p1;
        k_qkdyn<<<dim3(2, N_DYN), 256, 0, stream>>>(hc, wqd, bqd, wkd, bkd, qd, kd);
        k_attn_ctx<<<dim3(160, B), 256, 0, stream>>>(qs, ks, qd, kd, pc, ctx);
        k_rec<<<dim3(NN, 2), 128, 0, stream>>>(x, t, wri, bri, wro, bro, ctx, lin);
        k_gates_mm<<<dim3(NN, 2), 256, 0, stream>>>(lin, hc, wih, whh, gbuf);
        k_cell<<<dim3(NN, B), 256, 0, stream>>>(gbuf, bih, bhh, cc, hn, cn);
        k_sender<<<dim3(NN, 2), 128, 0, stream>>>(hn, wse, bse, px);
        k_proj<<<dim3(4, B), 256, 0, stream>>>(px, wp, bp, out, t);
    }
}